// Round 6
// baseline (143.141 us; speedup 1.0000x reference)
//
#include <hip/hip_runtime.h>

// SupConLoss on MI355X. features: [4096, 2, 128] fp32; labels: [4096] int; out: 1 f32.
//
// R5 changes vs R4:
//  - k_negsum: 544 strip-segment blocks (bi, up to 4 bj-tiles). A-frags in
//    registers loaded once/block; B tiles double-buffered in 2x32KB LDS with
//    one-barrier pipeline (stage k+1 after barrier -> overlaps compute of k).
//    Row sums accumulate in regs across tiles; row atomics once per block.
//  - k_zero folded into k_normalize; k_final folded into k_loss (done-counter,
//    device-scope release/acquire). 7 launches -> 4.
//
// ws layout: nf (2 MB) | neg_sum 8192 f32 | total f32 | done u32 | counts 100
//            | offsets 101 | classIdx 4096

#define BATCH 4096
#define NN    8192
#define DD    128
#define NCLS  100
#define MAXR  192
#define NB    64          // 8192/128 tiles per side
#define SEG   4
#define NSEG  544         // sum_{bi=0}^{63} ceil((64-bi)/4)
#define SCALE (1.0f / 0.07f)
#define LSLICE 8

typedef __attribute__((ext_vector_type(8))) short bf16x8;
typedef __attribute__((ext_vector_type(4))) float f32x4;

__device__ __forceinline__ unsigned short f2bf(float f) {
    unsigned u = __float_as_uint(f);
    u += 0x7FFF + ((u >> 16) & 1);
    return (unsigned short)(u >> 16);
}

// normalize + zero the accumulator region (neg_sum[8192], total, done)
__global__ void k_normalize(const float* __restrict__ feat, unsigned short* __restrict__ nf,
                            float* __restrict__ zeroReg) {
    int gi = blockIdx.x * 256 + threadIdx.x;
    if (gi < NN + 2) zeroReg[gi] = 0.0f;
    int wave = threadIdx.x >> 6, lane = threadIdx.x & 63;
    int row = blockIdx.x * 4 + wave;
    int v = row >> 12, b = row & (BATCH - 1);
    const float2* src = (const float2*)(feat + ((size_t)b * 2 + v) * DD);
    float2 x = src[lane];
    float ss = x.x * x.x + x.y * x.y;
    #pragma unroll
    for (int m = 32; m >= 1; m >>= 1) ss += __shfl_xor(ss, m, 64);
    float inv = rsqrtf(ss);
    ushort2 o;
    o.x = f2bf(x.x * inv);
    o.y = f2bf(x.y * inv);
    ((ushort2*)(nf + (size_t)row * DD))[lane] = o;
}

__global__ __launch_bounds__(256) void k_bucket(const int* __restrict__ labels,
                                                int* __restrict__ counts,
                                                int* __restrict__ offsets,
                                                int* __restrict__ classIdx) {
    __shared__ int cnt[NCLS], off[NCLS], cur[NCLS];
    int tid = threadIdx.x;
    for (int c = tid; c < NCLS; c += 256) cnt[c] = 0;
    __syncthreads();
    for (int b = tid; b < BATCH; b += 256) atomicAdd(&cnt[labels[b]], 1);
    __syncthreads();
    if (tid == 0) {
        int a = 0;
        for (int c = 0; c < NCLS; ++c) { off[c] = a; a += cnt[c]; }
    }
    __syncthreads();
    for (int c = tid; c < NCLS; c += 256) {
        cur[c] = 0;
        counts[c] = cnt[c];
        offsets[c] = off[c];
    }
    if (tid == 0) offsets[NCLS] = BATCH;
    __syncthreads();
    for (int b = tid; b < BATCH; b += 256) {
        int l = labels[b];
        int p = atomicAdd(&cur[l], 1);
        classIdx[off[l] + p] = b;
    }
}

// stage one 128x128 bf16 B-tile (rows bj*128..+127) into LDS buffer `buf`,
// XOR-swizzled: LDS slot (r, cS) holds global chunk (r, cS ^ (r&15)).
__device__ __forceinline__ void stage_tile(unsigned short* smem, const unsigned short* nf,
                                           int buf, int bj, int wave, int lane) {
    #pragma unroll
    for (int it = 0; it < 8; ++it) {
        int widx = wave * 8 + it;              // 0..31, 64 chunks each
        int chunkIdx = widx * 64 + lane;       // 0..2047
        int r = chunkIdx >> 4, cS = chunkIdx & 15;
        int cG = cS ^ (r & 15);
        const unsigned short* gp = nf + (size_t)(bj * 128 + r) * DD + cG * 8;
        unsigned short* lp = smem + (size_t)buf * 16384 + (size_t)widx * 512;
        __builtin_amdgcn_global_load_lds(
            (const __attribute__((address_space(1))) void*)gp,
            (__attribute__((address_space(3))) void*)lp, 16, 0, 0);
    }
}

// ---- pass 1: neg_sum[i] = sum_j exp(logit_ij) [lab(i)!=lab(j)], symmetric ----
__global__ __launch_bounds__(256, 2) void k_negsum(
        const unsigned short* __restrict__ nf,
        const int* __restrict__ labels,
        float* __restrict__ neg_sum) {
    __shared__ __attribute__((aligned(16))) unsigned short smem[2 * 128 * 128];  // 64 KB

    // decode segment id -> (bi, bj0, nt)
    int g = blockIdx.x, bi = 0;
    for (;;) {
        int n = (NB - bi + SEG - 1) / SEG;
        if (g < n) break;
        g -= n; ++bi;
    }
    int bj0 = bi + g * SEG;
    int nt = NB - bj0; if (nt > SEG) nt = SEG;

    int tid = threadIdx.x, wave = tid >> 6, lane = tid & 63;
    int wr = wave >> 1, wc = wave & 1;
    int q = lane >> 4, nq = lane & 15;
    const bf16x8* nfv = (const bf16x8*)nf;
    int rowBase = bi * 128 + wr * 64;

    // A frags: direct scattered global loads, once per block
    bf16x8 aF[4][4];
    #pragma unroll
    for (int rs = 0; rs < 4; ++rs) {
        int r = rowBase + rs * 16 + nq;
        #pragma unroll
        for (int s = 0; s < 4; ++s) aF[rs][s] = nfv[r * 16 + s * 4 + q];
    }
    int rlab[4][4];
    float rowsum[4][4];
    #pragma unroll
    for (int rs = 0; rs < 4; ++rs)
        #pragma unroll
        for (int rr = 0; rr < 4; ++rr) {
            rlab[rs][rr] = labels[(rowBase + rs * 16 + q * 4 + rr) & (BATCH - 1)];
            rowsum[rs][rr] = 0.0f;
        }

    stage_tile(smem, nf, 0, bj0, wave, lane);

    for (int k = 0; k < nt; ++k) {
        __syncthreads();                       // buf k&1 ready (drains last stage)
        if (k + 1 < nt) stage_tile(smem, nf, (k + 1) & 1, bj0 + k + 1, wave, lane);
        int bj = bj0 + k;
        bool diag = (bj == bi);
        const char* sB = (const char*)(smem + (size_t)(k & 1) * 16384);

        f32x4 acc[4][4];
        #pragma unroll
        for (int rs = 0; rs < 4; ++rs)
            #pragma unroll
            for (int cs = 0; cs < 4; ++cs) acc[rs][cs] = (f32x4){0.f, 0.f, 0.f, 0.f};
        #pragma unroll
        for (int s = 0; s < 4; ++s) {
            bf16x8 bF[4];
            #pragma unroll
            for (int cs = 0; cs < 4; ++cs) {
                int rB = wc * 64 + cs * 16 + nq;     // local row in tile
                int slot = rB * 16 + ((s * 4 + q) ^ nq);
                bF[cs] = *(const bf16x8*)(sB + slot * 16);
            }
            #pragma unroll
            for (int rs = 0; rs < 4; ++rs)
                #pragma unroll
                for (int cs = 0; cs < 4; ++cs)
                    acc[rs][cs] = __builtin_amdgcn_mfma_f32_16x16x32_bf16(
                        aF[rs][s], bF[cs], acc[rs][cs], 0, 0, 0);
        }

        int colBase = bj * 128 + wc * 64;
        // C/D layout: col = lane&15, row = (lane>>4)*4 + reg
        #pragma unroll
        for (int cs = 0; cs < 4; ++cs) {
            int col = colBase + cs * 16 + nq;
            int cl = labels[col & (BATCH - 1)];
            float colsum = 0.0f;
            #pragma unroll
            for (int rs = 0; rs < 4; ++rs)
                #pragma unroll
                for (int rr = 0; rr < 4; ++rr) {
                    float e = __expf(acc[rs][cs][rr] * SCALE);
                    float ev = (rlab[rs][rr] != cl) ? e : 0.0f;
                    rowsum[rs][rr] += ev;
                    colsum += ev;
                }
            if (!diag) {
                colsum += __shfl_xor(colsum, 16, 64);
                colsum += __shfl_xor(colsum, 32, 64);
                if (q == 0) atomicAdd(&neg_sum[col], colsum);
            }
        }
    }

    // row atomics once per block
    #pragma unroll
    for (int rs = 0; rs < 4; ++rs)
        #pragma unroll
        for (int rr = 0; rr < 4; ++rr) {
            float vsum = rowsum[rs][rr];
            vsum += __shfl_xor(vsum, 1, 64);
            vsum += __shfl_xor(vsum, 2, 64);
            vsum += __shfl_xor(vsum, 4, 64);
            vsum += __shfl_xor(vsum, 8, 64);
            if (nq == 0) atomicAdd(&neg_sum[rowBase + rs * 16 + q * 4 + rr], vsum);
        }
}

// ---- pass 2: pos pairs + fused finalize ----
__global__ __launch_bounds__(256) void k_loss(
        const unsigned short* __restrict__ nf,
        const int* __restrict__ counts, const int* __restrict__ offsets,
        const int* __restrict__ classIdx,
        const float* __restrict__ neg_sum,
        float* __restrict__ total, unsigned* __restrict__ done,
        float* __restrict__ out) {
    __shared__ int s_rows[MAXR];
    __shared__ __attribute__((aligned(16))) uint4 s_t[16][MAXR + 1];  // chunk-major
    int c = blockIdx.x;
    int m = counts[c], off = offsets[c];
    int twoM = 2 * m; if (twoM > MAXR) twoM = MAXR;
    int tid = threadIdx.x;
    for (int r = tid; r < twoM; r += 256) {
        int b = classIdx[off + (r < m ? r : r - m)];
        s_rows[r] = (r < m) ? b : b + BATCH;
    }
    __syncthreads();
    for (int ch = tid; ch < twoM * 16; ch += 256) {
        int r = ch >> 4, s = ch & 15;
        s_t[s][r] = ((const uint4*)(nf + (size_t)s_rows[r] * DD))[s];
    }
    __syncthreads();

    float partial = 0.0f;
    unsigned P = (unsigned)twoM * (unsigned)twoM;
    for (unsigned t = blockIdx.y * 256 + tid; t < P; t += 256 * LSLICE) {
        unsigned p = t / (unsigned)twoM;
        unsigned qq = t - p * (unsigned)twoM;
        if (p == qq) continue;
        float dot = 0.0f;
        #pragma unroll
        for (int s = 0; s < 16; ++s) {
            uint4 ua = s_t[s][p];    // wave-uniform broadcast
            uint4 ub = s_t[s][qq];   // consecutive lanes -> consecutive 16B
            const unsigned* pa = (const unsigned*)&ua;
            const unsigned* pb = (const unsigned*)&ub;
            #pragma unroll
            for (int w = 0; w < 4; ++w) {
                float a0 = __uint_as_float(pa[w] << 16);
                float a1 = __uint_as_float(pa[w] & 0xFFFF0000u);
                float b0 = __uint_as_float(pb[w] << 16);
                float b1 = __uint_as_float(pb[w] & 0xFFFF0000u);
                dot = fmaf(a0, b0, dot);
                dot = fmaf(a1, b1, dot);
            }
        }
        float logit = dot * SCALE;
        float ns = neg_sum[s_rows[qq]];
        partial += logit - __logf(ns + __expf(logit));
    }
    #pragma unroll
    for (int mm = 32; mm >= 1; mm >>= 1) partial += __shfl_xor(partial, mm, 64);
    __shared__ float red[4];
    if ((tid & 63) == 0) red[tid >> 6] = partial;
    __syncthreads();
    if (tid == 0) {
        atomicAdd(total, red[0] + red[1] + red[2] + red[3]);
        __threadfence();                           // release our total-add
        unsigned prev = __hip_atomic_fetch_add(done, 1u, __ATOMIC_ACQ_REL,
                                               __HIP_MEMORY_SCOPE_AGENT);
        if (prev == (unsigned)(NCLS * LSLICE - 1)) {
            float tot = __hip_atomic_load(total, __ATOMIC_ACQUIRE,
                                          __HIP_MEMORY_SCOPE_AGENT);
            out[0] = -tot * (1.0f / (float)NN);
        }
    }
}

extern "C" void kernel_launch(void* const* d_in, const int* in_sizes, int n_in,
                              void* d_out, int out_size, void* d_ws, size_t ws_size,
                              hipStream_t stream) {
    const float* feat = (const float*)d_in[0];
    const int* labels = (const int*)d_in[1];
    unsigned short* nf = (unsigned short*)d_ws;
    float* neg_sum = (float*)((char*)d_ws + (size_t)NN * DD * sizeof(unsigned short));
    float* total    = neg_sum + NN;           // 1
    unsigned* done  = (unsigned*)(total + 1); // 1
    int* counts     = (int*)(done + 1);       // 100
    int* offsets    = counts + NCLS;          // 101
    int* classIdx   = offsets + NCLS + 1;     // 4096
    float* out = (float*)d_out;

    hipLaunchKernelGGL(k_normalize, dim3(NN / 4), dim3(256), 0, stream, feat, nf, neg_sum);
    hipLaunchKernelGGL(k_bucket, dim3(1), dim3(256), 0, stream, labels, counts, offsets, classIdx);
    hipLaunchKernelGGL(k_negsum, dim3(NSEG), dim3(256), 0, stream, nf, labels, neg_sum);
    hipLaunchKernelGGL(k_loss, dim3(NCLS, LSLICE), dim3(256), 0, stream,
                       nf, counts, offsets, classIdx, neg_sum, total, done, out);
}

// Round 7
// 105.096 us; speedup vs baseline: 1.3620x; 1.3620x over previous
//
#include <hip/hip_runtime.h>

// SupConLoss on MI355X. features: [4096, 2, 128] fp32; labels: [4096] int; out: 1 f32.
//
// R6 changes vs R5:
//  - k_negsum: half-tile (64-col, 16 KB) double-buffered pipeline -> 32 KB LDS
//    (4-5 blocks/CU vs 2), waves 4x1 (32 rows each, A-frags halved, VGPR<=128
//    via __launch_bounds__(256,4)), SEG=2 -> 1056 blocks (fills 4/CU x 256).
//  - k_loss: per-class MFMA over staged member rows (clamped-row gather via
//    global_load_lds + XOR swizzle). No integer div, no scalar dots, grid 100.
//  - k_bucket: 1024 threads.
//
// ws layout: nf (2 MB) | neg_sum 8192 f32 | total f32 | done u32 | counts 100
//            | offsets 101 | classIdx 4096

#define BATCH 4096
#define NN    8192
#define DD    128
#define NCLS  100
#define MAXR  192
#define NB    64
#define SEG   2
#define NSEG  1056        // sum_{bi=0}^{63} ceil((64-bi)/2)
#define SCALE (1.0f / 0.07f)

typedef __attribute__((ext_vector_type(8))) short bf16x8;
typedef __attribute__((ext_vector_type(4))) float f32x4;

__device__ __forceinline__ unsigned short f2bf(float f) {
    unsigned u = __float_as_uint(f);
    u += 0x7FFF + ((u >> 16) & 1);
    return (unsigned short)(u >> 16);
}

// normalize + zero accumulator region (neg_sum[8192], total, done)
__global__ void k_normalize(const float* __restrict__ feat, unsigned short* __restrict__ nf,
                            float* __restrict__ zeroReg) {
    int gi = blockIdx.x * 256 + threadIdx.x;
    if (gi < NN + 2) zeroReg[gi] = 0.0f;
    int wave = threadIdx.x >> 6, lane = threadIdx.x & 63;
    int row = blockIdx.x * 4 + wave;
    int v = row >> 12, b = row & (BATCH - 1);
    const float2* src = (const float2*)(feat + ((size_t)b * 2 + v) * DD);
    float2 x = src[lane];
    float ss = x.x * x.x + x.y * x.y;
    #pragma unroll
    for (int m = 32; m >= 1; m >>= 1) ss += __shfl_xor(ss, m, 64);
    float inv = rsqrtf(ss);
    ushort2 o;
    o.x = f2bf(x.x * inv);
    o.y = f2bf(x.y * inv);
    ((ushort2*)(nf + (size_t)row * DD))[lane] = o;
}

__global__ __launch_bounds__(1024) void k_bucket(const int* __restrict__ labels,
                                                 int* __restrict__ counts,
                                                 int* __restrict__ offsets,
                                                 int* __restrict__ classIdx) {
    __shared__ int cnt[NCLS], off[NCLS], cur[NCLS];
    int tid = threadIdx.x;
    if (tid < NCLS) cnt[tid] = 0;
    __syncthreads();
    for (int b = tid; b < BATCH; b += 1024) atomicAdd(&cnt[labels[b]], 1);
    __syncthreads();
    if (tid == 0) {
        int a = 0;
        for (int c = 0; c < NCLS; ++c) { off[c] = a; a += cnt[c]; }
    }
    __syncthreads();
    if (tid < NCLS) {
        cur[tid] = 0;
        counts[tid] = cnt[tid];
        offsets[tid] = off[tid];
    }
    if (tid == 0) offsets[NCLS] = BATCH;
    __syncthreads();
    for (int b = tid; b < BATCH; b += 1024) {
        int l = labels[b];
        int p = atomicAdd(&cur[l], 1);
        classIdx[off[l] + p] = b;
    }
}

// stage one 64-row x 128-col bf16 half-tile into LDS buffer `buf` (16 KB),
// XOR-swizzled: LDS slot (r, cS) holds global chunk (r, cS ^ (r&15)).
__device__ __forceinline__ void stage_half(unsigned short* smem, const unsigned short* nf,
                                           int buf, int hrow, int wave, int lane) {
    #pragma unroll
    for (int it = 0; it < 4; ++it) {
        int widx = wave * 4 + it;              // 0..15
        int chunkIdx = widx * 64 + lane;       // 0..1023
        int r = chunkIdx >> 4, cS = chunkIdx & 15;
        int cG = cS ^ (r & 15);
        const unsigned short* gp = nf + (size_t)(hrow + r) * DD + cG * 8;
        unsigned short* lp = smem + (size_t)buf * 8192 + (size_t)widx * 512;
        __builtin_amdgcn_global_load_lds(
            (const __attribute__((address_space(1))) void*)gp,
            (__attribute__((address_space(3))) void*)lp, 16, 0, 0);
    }
}

// ---- pass 1: neg_sum[i] = sum_j exp(logit_ij) [lab(i)!=lab(j)], symmetric ----
__global__ __launch_bounds__(256, 4) void k_negsum(
        const unsigned short* __restrict__ nf,
        const int* __restrict__ labels,
        float* __restrict__ neg_sum) {
    __shared__ __attribute__((aligned(16))) unsigned short smem[2 * 64 * 128];  // 32 KB

    int g = blockIdx.x, bi = 0;
    for (;;) {
        int n = (NB - bi + SEG - 1) / SEG;
        if (g < n) break;
        g -= n; ++bi;
    }
    int bj0 = bi + g * SEG;
    int nt = NB - bj0; if (nt > SEG) nt = SEG;
    int nht = nt * 2;

    int tid = threadIdx.x, wave = tid >> 6, lane = tid & 63;
    int q = lane >> 4, nq = lane & 15;
    int rowW = bi * 128 + wave * 32;           // wave's 32-row base
    const bf16x8* nfv = (const bf16x8*)nf;

    // A frags (8): direct global, once per block
    bf16x8 aF[2][4];
    #pragma unroll
    for (int rs = 0; rs < 2; ++rs) {
        int r = rowW + rs * 16 + nq;
        #pragma unroll
        for (int s = 0; s < 4; ++s) aF[rs][s] = nfv[r * 16 + s * 4 + q];
    }
    int rlab[2][4];
    float rowsum[2][4];
    #pragma unroll
    for (int rs = 0; rs < 2; ++rs)
        #pragma unroll
        for (int rr = 0; rr < 4; ++rr) {
            rlab[rs][rr] = labels[(rowW + rs * 16 + q * 4 + rr) & (BATCH - 1)];
            rowsum[rs][rr] = 0.0f;
        }

    stage_half(smem, nf, 0, bj0 * 128, wave, lane);

    for (int ht = 0; ht < nht; ++ht) {
        __syncthreads();                       // buf ht&1 ready
        if (ht + 1 < nht) stage_half(smem, nf, (ht + 1) & 1, bj0 * 128 + (ht + 1) * 64, wave, lane);
        int bj = bj0 + (ht >> 1);
        bool diag = (bj == bi);
        const char* sB = (const char*)(smem + (size_t)(ht & 1) * 8192);

        f32x4 acc[2][4];
        #pragma unroll
        for (int rs = 0; rs < 2; ++rs)
            #pragma unroll
            for (int cs = 0; cs < 4; ++cs) acc[rs][cs] = (f32x4){0.f, 0.f, 0.f, 0.f};
        #pragma unroll
        for (int s = 0; s < 4; ++s) {
            bf16x8 bF[4];
            #pragma unroll
            for (int cs = 0; cs < 4; ++cs) {
                int rB = cs * 16 + nq;                       // local row in half-tile
                int slot = rB * 16 + ((s * 4 + q) ^ nq);
                bF[cs] = *(const bf16x8*)(sB + slot * 16);
            }
            #pragma unroll
            for (int rs = 0; rs < 2; ++rs)
                #pragma unroll
                for (int cs = 0; cs < 4; ++cs)
                    acc[rs][cs] = __builtin_amdgcn_mfma_f32_16x16x32_bf16(
                        aF[rs][s], bF[cs], acc[rs][cs], 0, 0, 0);
        }

        int colBase = bj0 * 128 + ht * 64;
        // C/D layout: col = lane&15, row = (lane>>4)*4 + reg
        #pragma unroll
        for (int cs = 0; cs < 4; ++cs) {
            int col = colBase + cs * 16 + nq;
            int cl = labels[col & (BATCH - 1)];
            float colsum = 0.0f;
            #pragma unroll
            for (int rs = 0; rs < 2; ++rs)
                #pragma unroll
                for (int rr = 0; rr < 4; ++rr) {
                    float e = __expf(acc[rs][cs][rr] * SCALE);
                    float ev = (rlab[rs][rr] != cl) ? e : 0.0f;
                    rowsum[rs][rr] += ev;
                    colsum += ev;
                }
            if (!diag) {
                colsum += __shfl_xor(colsum, 16, 64);
                colsum += __shfl_xor(colsum, 32, 64);
                if (q == 0) atomicAdd(&neg_sum[col], colsum);
            }
        }
    }

    #pragma unroll
    for (int rs = 0; rs < 2; ++rs)
        #pragma unroll
        for (int rr = 0; rr < 4; ++rr) {
            float vsum = rowsum[rs][rr];
            vsum += __shfl_xor(vsum, 1, 64);
            vsum += __shfl_xor(vsum, 2, 64);
            vsum += __shfl_xor(vsum, 4, 64);
            vsum += __shfl_xor(vsum, 8, 64);
            if (nq == 0) atomicAdd(&neg_sum[rowW + rs * 16 + q * 4 + rr], vsum);
        }
}

// ---- pass 2: per-class MFMA over member rows + fused finalize ----
__global__ __launch_bounds__(256) void k_loss(
        const unsigned short* __restrict__ nf,
        const int* __restrict__ counts, const int* __restrict__ offsets,
        const int* __restrict__ classIdx,
        const float* __restrict__ neg_sum,
        float* __restrict__ total, unsigned* __restrict__ done,
        float* __restrict__ out) {
    __shared__ __attribute__((aligned(16))) unsigned short s_feat[MAXR * 128]; // 48 KB
    __shared__ int s_rows[MAXR];
    __shared__ float s_ns[MAXR];
    __shared__ float red[4];

    int c = blockIdx.x;
    int m = counts[c], off = offsets[c];
    int twoM = 2 * m; if (twoM > MAXR) twoM = MAXR;
    int tid = threadIdx.x, wave = tid >> 6, lane = tid & 63;
    int q = lane >> 4, nq = lane & 15;

    for (int r = tid; r < twoM; r += 256) {
        int b = classIdx[off + (r < m ? r : r - m)];
        int row = (r < m) ? b : b + BATCH;
        s_rows[r] = row;
        s_ns[r] = neg_sum[row];
    }
    __syncthreads();    // s_rows ready before gather staging

    int ntile = (twoM + 63) >> 6;            // 1..3
    int nchunk = ntile * 64 * 16;
    // gather-stage rows (clamped: r>=twoM duplicates last row; masked later)
    for (int widx = wave; widx * 64 < nchunk; widx += 4) {
        int chunkIdx = widx * 64 + lane;
        int r = chunkIdx >> 4, cS = chunkIdx & 15;
        int cG = cS ^ (r & 15);
        int rc = r < twoM ? r : twoM - 1;
        const unsigned short* gp = nf + (size_t)s_rows[rc] * DD + cG * 8;
        unsigned short* lp = s_feat + (size_t)widx * 512;
        __builtin_amdgcn_global_load_lds(
            (const __attribute__((address_space(1))) void*)gp,
            (__attribute__((address_space(3))) void*)lp, 16, 0, 0);
    }
    __syncthreads();

    const char* sB = (const char*)s_feat;
    float partial = 0.0f;
    int npairs = ntile * ntile;
    for (int pp = wave; pp < npairs; pp += 4) {
        int ti = pp / ntile, tj = pp - ti * ntile;
        bf16x8 aF[4][4];
        #pragma unroll
        for (int rs = 0; rs < 4; ++rs) {
            int rA = ti * 64 + rs * 16 + nq;
            #pragma unroll
            for (int s = 0; s < 4; ++s) {
                int slot = rA * 16 + ((s * 4 + q) ^ nq);
                aF[rs][s] = *(const bf16x8*)(sB + slot * 16);
            }
        }
        f32x4 acc[4][4];
        #pragma unroll
        for (int rs = 0; rs < 4; ++rs)
            #pragma unroll
            for (int cs = 0; cs < 4; ++cs) acc[rs][cs] = (f32x4){0.f, 0.f, 0.f, 0.f};
        #pragma unroll
        for (int s = 0; s < 4; ++s) {
            bf16x8 bF[4];
            #pragma unroll
            for (int cs = 0; cs < 4; ++cs) {
                int rB = tj * 64 + cs * 16 + nq;
                int slot = rB * 16 + ((s * 4 + q) ^ nq);
                bF[cs] = *(const bf16x8*)(sB + slot * 16);
            }
            #pragma unroll
            for (int rs = 0; rs < 4; ++rs)
                #pragma unroll
                for (int cs = 0; cs < 4; ++cs)
                    acc[rs][cs] = __builtin_amdgcn_mfma_f32_16x16x32_bf16(
                        aF[rs][s], bF[cs], acc[rs][cs], 0, 0, 0);
        }
        #pragma unroll
        for (int cs = 0; cs < 4; ++cs) {
            int qq = tj * 64 + cs * 16 + nq;
            float ns = s_ns[qq < twoM ? qq : 0];
            #pragma unroll
            for (int rs = 0; rs < 4; ++rs)
                #pragma unroll
                for (int rr = 0; rr < 4; ++rr) {
                    int p = ti * 64 + rs * 16 + q * 4 + rr;
                    bool valid = (p < twoM) && (qq < twoM) && (p != qq);
                    float logit = acc[rs][cs][rr] * SCALE;
                    float term = logit - __logf(ns + __expf(logit));
                    partial += valid ? term : 0.0f;
                }
        }
    }
    #pragma unroll
    for (int mm = 32; mm >= 1; mm >>= 1) partial += __shfl_xor(partial, mm, 64);
    if (lane == 0) red[wave] = partial;
    __syncthreads();
    if (tid == 0) {
        atomicAdd(total, red[0] + red[1] + red[2] + red[3]);
        __threadfence();
        unsigned prev = __hip_atomic_fetch_add(done, 1u, __ATOMIC_ACQ_REL,
                                               __HIP_MEMORY_SCOPE_AGENT);
        if (prev == (unsigned)(NCLS - 1)) {
            float tot = __hip_atomic_load(total, __ATOMIC_ACQUIRE,
                                          __HIP_MEMORY_SCOPE_AGENT);
            out[0] = -tot * (1.0f / (float)NN);
        }
    }
}

extern "C" void kernel_launch(void* const* d_in, const int* in_sizes, int n_in,
                              void* d_out, int out_size, void* d_ws, size_t ws_size,
                              hipStream_t stream) {
    const float* feat = (const float*)d_in[0];
    const int* labels = (const int*)d_in[1];
    unsigned short* nf = (unsigned short*)d_ws;
    float* neg_sum = (float*)((char*)d_ws + (size_t)NN * DD * sizeof(unsigned short));
    float* total    = neg_sum + NN;           // 1
    unsigned* done  = (unsigned*)(total + 1); // 1
    int* counts     = (int*)(done + 1);       // 100
    int* offsets    = counts + NCLS;          // 101
    int* classIdx   = offsets + NCLS + 1;     // 4096
    float* out = (float*)d_out;

    hipLaunchKernelGGL(k_normalize, dim3(NN / 4), dim3(256), 0, stream, feat, nf, neg_sum);
    hipLaunchKernelGGL(k_bucket, dim3(1), dim3(1024), 0, stream, labels, counts, offsets, classIdx);
    hipLaunchKernelGGL(k_negsum, dim3(NSEG), dim3(256), 0, stream, nf, labels, neg_sum);
    hipLaunchKernelGGL(k_loss, dim3(NCLS), dim3(256), 0, stream,
                       nf, counts, offsets, classIdx, neg_sum, total, done, out);
}